// Round 1
// baseline (1459.602 us; speedup 1.0000x reference)
//
#include <hip/hip_runtime.h>

// ============================================================================
// TransformerSubsetAggregator on MI355X (gfx950)
// N_CHAINS=8192, L=128, N=100000, D=256, K=8, H=4, dh=64, FF=1024
// Strategy: top-k select+gather (fp32) -> transformer layer + head with
// bf16 MFMA (16x16x32) GEMMs, fp32 LN/softmax/residual/accumulate.
// ws layout: X fp32 64MB | NPICK | bf16 weight copies (~2.7MB). Total ~69.8MB.
// ============================================================================

#define DIM   256
#define LSEQ  128
#define KTOK  8

typedef __bf16 bf16x8 __attribute__((ext_vector_type(8)));
typedef float  f32x4  __attribute__((ext_vector_type(4)));

__device__ __forceinline__ f32x4 mfma16(bf16x8 a, bf16x8 b, f32x4 c) {
  // gfx950: A/B frag: idx m(or n)=lane&15, k=(lane>>4)*8+j (K-contiguous 16B)
  // D frag: col=lane&15, row=(lane>>4)*4+reg   [verified layouts, learn_hip m89/m91]
  return __builtin_amdgcn_mfma_f32_16x16x32_bf16(a, b, c, 0, 0, 0);
}

__device__ __forceinline__ unsigned short f2bf(float f) {
  unsigned u = __float_as_uint(f);
  u = (u + 0x7FFFu + ((u >> 16) & 1u)) >> 16;   // RNE
  return (unsigned short)u;
}

// ---------------------------------------------------------------------------
// k_prep: fp32 -> bf16 weight conversion (w_out1 padded K 257 -> 288, zeros)
// ---------------------------------------------------------------------------
#define PREP_TOTAL 1343488
__global__ __launch_bounds__(256) void k_prep(
    const float* __restrict__ wqkv, const float* __restrict__ wo,
    const float* __restrict__ wff1, const float* __restrict__ wff2,
    const float* __restrict__ wout1, const float* __restrict__ wout2,
    unsigned short* __restrict__ oq, unsigned short* __restrict__ oo,
    unsigned short* __restrict__ of1, unsigned short* __restrict__ of2,
    unsigned short* __restrict__ oo1, unsigned short* __restrict__ oo2)
{
  int i = blockIdx.x * 256 + threadIdx.x;
  if (i < 196608) { oq[i] = f2bf(wqkv[i]); return; }
  i -= 196608;
  if (i < 65536)  { oo[i] = f2bf(wo[i]); return; }
  i -= 65536;
  if (i < 262144) { of1[i] = f2bf(wff1[i]); return; }
  i -= 262144;
  if (i < 262144) { of2[i] = f2bf(wff2[i]); return; }
  i -= 262144;
  if (i < 294912) {
    int r = i / 288, cidx = i - r * 288;
    oo1[i] = (cidx < 257) ? f2bf(wout1[r * 257 + cidx]) : (unsigned short)0;
    return;
  }
  i -= 294912;
  if (i < 262144) { oo2[i] = f2bf(wout2[i]); }
}

// ---------------------------------------------------------------------------
// k_sel: per-chain top-8 (exact lax.top_k tie semantics: value desc, idx asc),
// sort picked positions ascending, gather v rows + pos_embed -> X.
// After the sort, picked slots are exactly j < npick (matches reference's
// sort-then-compact with sentinel L).
// ---------------------------------------------------------------------------
__global__ __launch_bounds__(256) void k_sel(
    const float* __restrict__ v, const int* __restrict__ batch_idx,
    const int* __restrict__ mask, const float* __restrict__ rank_scores,
    const float* __restrict__ pos_embed,
    float* __restrict__ X, int* __restrict__ NPICK)
{
  const int c = blockIdx.x;
  const int tid = threadIdx.x;
  __shared__ int s_mem[KTOK];
  __shared__ int s_np;

  if (tid < 64) {
    const int l = tid;
    unsigned long long key[2];
    #pragma unroll
    for (int t = 0; t < 2; ++t) {
      int p = l + 64 * t;
      int mk = mask[c * LSEQ + p];
      float s = rank_scores[c * LSEQ + p];
      unsigned u = __float_as_uint(s);
      u = (u & 0x80000000u) ? ~u : (u | 0x80000000u);   // order-preserving map
      unsigned long long kk =
          ((unsigned long long)u << 32) | (unsigned long long)(0xFFFFFFFFu - (unsigned)p);
      key[t] = mk ? kk : 0ull;
    }
    int w[KTOK];
    #pragma unroll
    for (int r = 0; r < KTOK; ++r) w[r] = 0x7FFFFFFF;
    int np = 0;
    for (int r = 0; r < KTOK; ++r) {
      unsigned long long best = key[0] > key[1] ? key[0] : key[1];
      for (int off = 32; off > 0; off >>= 1) {
        unsigned long long o = __shfl_xor(best, off, 64);
        if (o > best) best = o;
      }
      if (best == 0ull) break;
      int idx = (int)(0xFFFFFFFFu - (unsigned)(best & 0xFFFFFFFFull));
      w[np++] = idx;
      if (key[0] == best) key[0] = 0ull;
      if (key[1] == best) key[1] = 0ull;
    }
    // sort ascending (fixed-index network; invalid slots are 0x7FFFFFFF)
    #pragma unroll
    for (int a = 0; a < KTOK - 1; ++a)
      #pragma unroll
      for (int b2 = 0; b2 < KTOK - 1 - a; ++b2) {
        int x0 = w[b2], x1 = w[b2 + 1];
        w[b2] = min(x0, x1); w[b2 + 1] = max(x0, x1);
      }
    if (l < KTOK) {
      s_mem[l] = (l < np) ? batch_idx[c * LSEQ + w[l]] : -1;
    }
    if (l == 0) { s_np = np; NPICK[c] = np; }
  }
  __syncthreads();

  const int np = s_np;
  const int j = tid >> 5, q = tid & 31;
  const int r = s_mem[j];
  const float4* v4  = (const float4*)v;
  const float4* pe4 = (const float4*)pos_embed;
  float4* X4 = (float4*)X;
  #pragma unroll
  for (int rep = 0; rep < 2; ++rep) {
    int f = q + rep * 32;                     // float4 index within row (0..63)
    float4 pe = pe4[j * 64 + f];
    float4 val = make_float4(0.f, 0.f, 0.f, 0.f);
    if (j < np) val = v4[(long)r * 64 + f];
    float4 o;
    o.x = val.x + pe.x; o.y = val.y + pe.y; o.z = val.z + pe.z; o.w = val.w + pe.w;
    X4[((long)c * KTOK + j) * 64 + f] = o;
  }
}

// ---------------------------------------------------------------------------
// k_layer: one transformer encoder layer per 8 chains (64 tokens) per block.
// ---------------------------------------------------------------------------
#define SAPAD 264   // 256 + 8 bf16 pad (breaks LDS bank aliasing, keeps 16B align)
#define SKVP  520   // 512 + 8
#define SGP   72    // 64 + 8

__device__ __forceinline__ void layernorm_to_lds(
    const float* __restrict__ X, long tokbase,
    const float* __restrict__ g, const float* __restrict__ b,
    unsigned short* sA, int tid)
{
  const int r = tid >> 2, p = tid & 3;
  const float4* xr = (const float4*)(X + (tokbase + r) * DIM + p * 64);
  float sum = 0.f, ss = 0.f;
  #pragma unroll
  for (int i = 0; i < 16; ++i) {
    float4 t = xr[i];
    sum += t.x + t.y + t.z + t.w;
    ss  += t.x * t.x + t.y * t.y + t.z * t.z + t.w * t.w;
  }
  sum += __shfl_xor(sum, 1); ss += __shfl_xor(ss, 1);
  sum += __shfl_xor(sum, 2); ss += __shfl_xor(ss, 2);
  const float mu = sum * (1.f / 256.f);
  const float var = ss * (1.f / 256.f) - mu * mu;
  const float rstd = rsqrtf(var + 1e-5f);
  #pragma unroll
  for (int i = 0; i < 16; ++i) {
    float4 t = xr[i];
    int col = p * 64 + i * 4;
    ushort4 hv;
    hv.x = f2bf((t.x - mu) * rstd * g[col + 0] + b[col + 0]);
    hv.y = f2bf((t.y - mu) * rstd * g[col + 1] + b[col + 1]);
    hv.z = f2bf((t.z - mu) * rstd * g[col + 2] + b[col + 2]);
    hv.w = f2bf((t.w - mu) * rstd * g[col + 3] + b[col + 3]);
    *(ushort4*)&sA[r * SAPAD + col] = hv;
  }
}

__global__ __launch_bounds__(256) void k_layer(
    float* __restrict__ X, const int* __restrict__ NPICK,
    const unsigned short* __restrict__ wqkv, const unsigned short* __restrict__ wo,
    const unsigned short* __restrict__ wff1, const unsigned short* __restrict__ wff2,
    const float* __restrict__ bqkv, const float* __restrict__ bo,
    const float* __restrict__ ln1g, const float* __restrict__ ln1b,
    const float* __restrict__ ln2g, const float* __restrict__ ln2b,
    const float* __restrict__ bff1, const float* __restrict__ bff2)
{
  __shared__ unsigned short sA[64 * SAPAD];   // h (LN1), later h2 (LN2)
  __shared__ unsigned short sQ[64 * SAPAD];   // q, later attention output o
  __shared__ unsigned short sKV[64 * SKVP];   // cols 0..255 = k, 256..511 = v
  __shared__ unsigned short sG[64 * SGP];     // gelu(FF1) tile (wave-private rows)
  __shared__ int s_np[8];

  const int tid = threadIdx.x;
  const int blk = blockIdx.x;
  const long tokbase = (long)blk * 64;

  if (tid < 8) s_np[tid] = NPICK[blk * 8 + tid];

  layernorm_to_lds(X, tokbase, ln1g, ln1b, sA, tid);
  __syncthreads();

  const int wv = tid >> 6, ln = tid & 63;
  const int lr = ln & 15, lq = ln >> 4;
  const int m0 = wv * 16;
  const f32x4 vzero = {0.f, 0.f, 0.f, 0.f};

  // ---- QKV GEMM: [64,256] @ [768,256]^T ----
  for (int chunk = 0; chunk < 12; ++chunk) {
    const int n0 = chunk * 64;
    f32x4 acc[4];
    #pragma unroll
    for (int nt = 0; nt < 4; ++nt) acc[nt] = vzero;
    #pragma unroll
    for (int s = 0; s < 8; ++s) {
      bf16x8 a = *(const bf16x8*)&sA[(m0 + lr) * SAPAD + s * 32 + lq * 8];
      #pragma unroll
      for (int nt = 0; nt < 4; ++nt) {
        bf16x8 b = *(const bf16x8*)&wqkv[(n0 + nt * 16 + lr) * 256 + s * 32 + lq * 8];
        acc[nt] = mfma16(a, b, acc[nt]);
      }
    }
    #pragma unroll
    for (int nt = 0; nt < 4; ++nt) {
      const int n = n0 + nt * 16 + lr;
      const float bias = bqkv[n];
      #pragma unroll
      for (int reg = 0; reg < 4; ++reg) {
        const int row = m0 + lq * 4 + reg;
        const unsigned short hv = f2bf(acc[nt][reg] + bias);
        if (chunk < 4)      sQ[row * SAPAD + n] = hv;
        else if (chunk < 8) sKV[row * SKVP + (n - 256)] = hv;
        else                sKV[row * SKVP + 256 + (n - 512)] = hv;
      }
    }
  }
  __syncthreads();

  // ---- attention: thread = (chain c, head hh, query qi) ----
  {
    const int c = tid >> 5, hh = (tid >> 3) & 3, qi = tid & 7;
    const int natt = max(1, s_np[c]);          // kpm[:,0] forced-attend if empty
    const int qrow = c * 8 + qi;
    float sc[8];
    #pragma unroll
    for (int j = 0; j < 8; ++j) sc[j] = -1e30f;
    for (int j = 0; j < natt; ++j) {
      float d = 0.f;
      #pragma unroll
      for (int dc = 0; dc < 8; ++dc) {
        bf16x8 qv = *(const bf16x8*)&sQ[qrow * SAPAD + hh * 64 + dc * 8];
        bf16x8 kv = *(const bf16x8*)&sKV[(c * 8 + j) * SKVP + hh * 64 + dc * 8];
        #pragma unroll
        for (int e = 0; e < 8; ++e) d += (float)qv[e] * (float)kv[e];
      }
      sc[j] = d * 0.125f;                      // 1/sqrt(64)
    }
    float mx = -1e30f;
    #pragma unroll
    for (int j = 0; j < 8; ++j) mx = fmaxf(mx, sc[j]);
    float pr[8]; float ssum = 0.f;
    #pragma unroll
    for (int j = 0; j < 8; ++j) {
      float e = (j < natt) ? __expf(sc[j] - mx) : 0.f;
      pr[j] = e; ssum += e;
    }
    const float inv = 1.f / ssum;
    #pragma unroll
    for (int dc = 0; dc < 8; ++dc) {
      float o8[8] = {0.f,0.f,0.f,0.f,0.f,0.f,0.f,0.f};
      for (int j = 0; j < natt; ++j) {
        const float pj = pr[j] * inv;
        bf16x8 vv = *(const bf16x8*)&sKV[(c * 8 + j) * SKVP + 256 + hh * 64 + dc * 8];
        #pragma unroll
        for (int e = 0; e < 8; ++e) o8[e] += pj * (float)vv[e];
      }
      ushort4 h0, h1;
      h0.x = f2bf(o8[0]); h0.y = f2bf(o8[1]); h0.z = f2bf(o8[2]); h0.w = f2bf(o8[3]);
      h1.x = f2bf(o8[4]); h1.y = f2bf(o8[5]); h1.z = f2bf(o8[6]); h1.w = f2bf(o8[7]);
      // overwrite this thread's own q region (only this thread reads/writes it)
      *(ushort4*)&sQ[qrow * SAPAD + hh * 64 + dc * 8 + 0] = h0;
      *(ushort4*)&sQ[qrow * SAPAD + hh * 64 + dc * 8 + 4] = h1;
    }
  }
  __syncthreads();

  // ---- o @ w_o^T + b_o + residual -> X (in place) ----
  {
    f32x4 acc2[16];
    #pragma unroll
    for (int nt = 0; nt < 16; ++nt) acc2[nt] = vzero;
    #pragma unroll
    for (int s = 0; s < 8; ++s) {
      bf16x8 a = *(const bf16x8*)&sQ[(m0 + lr) * SAPAD + s * 32 + lq * 8];
      #pragma unroll
      for (int nt = 0; nt < 16; ++nt) {
        bf16x8 b = *(const bf16x8*)&wo[(nt * 16 + lr) * 256 + s * 32 + lq * 8];
        acc2[nt] = mfma16(a, b, acc2[nt]);
      }
    }
    #pragma unroll
    for (int nt = 0; nt < 16; ++nt) {
      const int col = nt * 16 + lr;
      const float bias = bo[col];
      #pragma unroll
      for (int reg = 0; reg < 4; ++reg) {
        const int row = m0 + lq * 4 + reg;
        const long gi = (tokbase + row) * DIM + col;
        X[gi] = X[gi] + acc2[nt][reg] + bias;
      }
    }
  }
  __syncthreads();

  layernorm_to_lds(X, tokbase, ln2g, ln2b, sA, tid);
  __syncthreads();

  // ---- FF: x += gelu(h2 @ w_ff1^T + b1) @ w_ff2^T + b2, chunked over FF ----
  {
    f32x4 acc3[16];
    #pragma unroll
    for (int nt = 0; nt < 16; ++nt) acc3[nt] = vzero;
    for (int f = 0; f < 16; ++f) {
      f32x4 ga[4];
      #pragma unroll
      for (int nt = 0; nt < 4; ++nt) ga[nt] = vzero;
      #pragma unroll
      for (int s = 0; s < 8; ++s) {
        bf16x8 a = *(const bf16x8*)&sA[(m0 + lr) * SAPAD + s * 32 + lq * 8];
        #pragma unroll
        for (int nt = 0; nt < 4; ++nt) {
          bf16x8 b = *(const bf16x8*)&wff1[(f * 64 + nt * 16 + lr) * 256 + s * 32 + lq * 8];
          ga[nt] = mfma16(a, b, ga[nt]);
        }
      }
      #pragma unroll
      for (int nt = 0; nt < 4; ++nt) {
        const int n = f * 64 + nt * 16 + lr;
        const float bias = bff1[n];
        #pragma unroll
        for (int reg = 0; reg < 4; ++reg) {
          const float val = ga[nt][reg] + bias;
          const float gl = 0.5f * val * (1.f + erff(val * 0.70710678118654752f));
          sG[(m0 + lq * 4 + reg) * SGP + nt * 16 + lr] = f2bf(gl);
        }
      }
      __syncthreads();   // also keeps waves lockstep for L1 reuse on B loads
      #pragma unroll
      for (int s2 = 0; s2 < 2; ++s2) {
        bf16x8 a = *(const bf16x8*)&sG[(m0 + lr) * SGP + s2 * 32 + lq * 8];
        #pragma unroll
        for (int nt = 0; nt < 16; ++nt) {
          bf16x8 b = *(const bf16x8*)&wff2[(nt * 16 + lr) * 1024 + f * 64 + s2 * 32 + lq * 8];
          acc3[nt] = mfma16(a, b, acc3[nt]);
        }
      }
    }
    #pragma unroll
    for (int nt = 0; nt < 16; ++nt) {
      const int col = nt * 16 + lr;
      const float bias = bff2[col];
      #pragma unroll
      for (int reg = 0; reg < 4; ++reg) {
        const int row = m0 + lq * 4 + reg;
        const long gi = (tokbase + row) * DIM + col;
        X[gi] = X[gi] + acc3[nt][reg] + bias;
      }
    }
  }
}

// ---------------------------------------------------------------------------
// k_head: masked mean-pool + [pooled, log1p(count)] -> MLP head -> d_out
// ---------------------------------------------------------------------------
#define SFP 296   // 288 + 8

__global__ __launch_bounds__(256) void k_head(
    const float* __restrict__ X, const int* __restrict__ NPICK,
    const float* __restrict__ count,
    const unsigned short* __restrict__ wout1, const unsigned short* __restrict__ wout2,
    const float* __restrict__ bout1, const float* __restrict__ bout2,
    float* __restrict__ out)
{
  __shared__ unsigned short sF[64 * SFP];   // feat [64 chains][288] bf16
  __shared__ unsigned short sG[64 * SGP];

  const int tid = threadIdx.x;
  const int blk = blockIdx.x;

  // pooled: thread = (chain cc, quarter p)
  {
    const int cc = tid >> 2, p = tid & 3;
    const int chain = blk * 64 + cc;
    const int np = NPICK[chain];
    const float inv = (np > 0) ? (1.f / (float)np) : 0.f;
    const float4* xb = (const float4*)(X + ((long)chain * KTOK) * DIM + p * 64);
    #pragma unroll
    for (int i = 0; i < 16; ++i) {
      float4 s = make_float4(0.f, 0.f, 0.f, 0.f);
      for (int j = 0; j < np; ++j) {
        float4 t = xb[j * 64 + i];    // row stride 256 floats = 64 float4
        s.x += t.x; s.y += t.y; s.z += t.z; s.w += t.w;
      }
      ushort4 hv;
      hv.x = f2bf(s.x * inv); hv.y = f2bf(s.y * inv);
      hv.z = f2bf(s.z * inv); hv.w = f2bf(s.w * inv);
      *(ushort4*)&sF[cc * SFP + p * 64 + i * 4] = hv;
    }
    if (p == 3) {
      sF[cc * SFP + 256] = f2bf(log1pf(count[chain]));
      #pragma unroll
      for (int col = 257; col < 288; ++col) sF[cc * SFP + col] = 0;
    }
  }
  __syncthreads();

  const int wv = tid >> 6, ln = tid & 63;
  const int lr = ln & 15, lq = ln >> 4;
  const int m0 = wv * 16;
  const f32x4 vzero = {0.f, 0.f, 0.f, 0.f};

  f32x4 oacc[16];
  #pragma unroll
  for (int nt = 0; nt < 16; ++nt) oacc[nt] = vzero;

  for (int f = 0; f < 16; ++f) {
    f32x4 ga[4];
    #pragma unroll
    for (int nt = 0; nt < 4; ++nt) ga[nt] = vzero;
    #pragma unroll
    for (int s = 0; s < 9; ++s) {             // K = 288
      bf16x8 a = *(const bf16x8*)&sF[(m0 + lr) * SFP + s * 32 + lq * 8];
      #pragma unroll
      for (int nt = 0; nt < 4; ++nt) {
        bf16x8 b = *(const bf16x8*)&wout1[(f * 64 + nt * 16 + lr) * 288 + s * 32 + lq * 8];
        ga[nt] = mfma16(a, b, ga[nt]);
      }
    }
    #pragma unroll
    for (int nt = 0; nt < 4; ++nt) {
      const int n = f * 64 + nt * 16 + lr;
      const float bias = bout1[n];
      #pragma unroll
      for (int reg = 0; reg < 4; ++reg) {
        const float val = ga[nt][reg] + bias;
        const float gl = 0.5f * val * (1.f + erff(val * 0.70710678118654752f));
        sG[(m0 + lq * 4 + reg) * SGP + nt * 16 + lr] = f2bf(gl);
      }
    }
    __syncthreads();
    #pragma unroll
    for (int s2 = 0; s2 < 2; ++s2) {
      bf16x8 a = *(const bf16x8*)&sG[(m0 + lr) * SGP + s2 * 32 + lq * 8];
      #pragma unroll
      for (int nt = 0; nt < 16; ++nt) {
        bf16x8 b = *(const bf16x8*)&wout2[(nt * 16 + lr) * 1024 + f * 64 + s2 * 32 + lq * 8];
        oacc[nt] = mfma16(a, b, oacc[nt]);
      }
    }
  }
  #pragma unroll
  for (int nt = 0; nt < 16; ++nt) {
    const int col = nt * 16 + lr;
    const float bias = bout2[col];
    #pragma unroll
    for (int reg = 0; reg < 4; ++reg) {
      const int row = m0 + lq * 4 + reg;
      out[((long)blk * 64 + row) * DIM + col] = oacc[nt][reg] + bias;
    }
  }
}

// ---------------------------------------------------------------------------
extern "C" void kernel_launch(void* const* d_in, const int* in_sizes, int n_in,
                              void* d_out, int out_size, void* d_ws, size_t ws_size,
                              hipStream_t stream) {
  (void)in_sizes; (void)n_in; (void)out_size; (void)ws_size;
  const float* v          = (const float*)d_in[0];
  const int*   batch_idx  = (const int*)  d_in[1];
  const int*   mask       = (const int*)  d_in[2];
  const float* count      = (const float*)d_in[3];
  const float* rank       = (const float*)d_in[4];
  const float* pe         = (const float*)d_in[5];
  const float* w_qkv      = (const float*)d_in[6];
  const float* b_qkv      = (const float*)d_in[7];
  const float* w_o        = (const float*)d_in[8];
  const float* b_o        = (const float*)d_in[9];
  const float* ln1g       = (const float*)d_in[10];
  const float* ln1b       = (const float*)d_in[11];
  const float* ln2g       = (const float*)d_in[12];
  const float* ln2b       = (const float*)d_in[13];
  const float* w_ff1      = (const float*)d_in[14];
  const float* b_ff1      = (const float*)d_in[15];
  const float* w_ff2      = (const float*)d_in[16];
  const float* b_ff2      = (const float*)d_in[17];
  const float* w_out1     = (const float*)d_in[18];
  const float* b_out1     = (const float*)d_in[19];
  const float* w_out2     = (const float*)d_in[20];
  const float* b_out2     = (const float*)d_in[21];
  float* out = (float*)d_out;

  char* ws = (char*)d_ws;
  float* X      = (float*)ws;                               // 67,108,864 B
  int*   NPICK  = (int*)(ws + 67108864);                    // 32,768 B
  unsigned short* wq_bf   = (unsigned short*)(ws + 67141632); // 393,216 B
  unsigned short* wo_bf   = (unsigned short*)(ws + 67534848); // 131,072 B
  unsigned short* wff1_bf = (unsigned short*)(ws + 67665920); // 524,288 B
  unsigned short* wff2_bf = (unsigned short*)(ws + 68190208); // 524,288 B
  unsigned short* wo1_bf  = (unsigned short*)(ws + 68714496); // 589,824 B (padded 1024x288)
  unsigned short* wo2_bf  = (unsigned short*)(ws + 69304320); // 524,288 B  -> total 69,828,608 B

  k_prep<<<(PREP_TOTAL + 255) / 256, 256, 0, stream>>>(
      w_qkv, w_o, w_ff1, w_ff2, w_out1, w_out2,
      wq_bf, wo_bf, wff1_bf, wff2_bf, wo1_bf, wo2_bf);

  k_sel<<<8192, 256, 0, stream>>>(v, batch_idx, mask, rank, pe, X, NPICK);

  k_layer<<<1024, 256, 0, stream>>>(X, NPICK,
      wq_bf, wo_bf, wff1_bf, wff2_bf,
      b_qkv, b_o, ln1g, ln1b, ln2g, ln2b, b_ff1, b_ff2);

  k_head<<<128, 256, 0, stream>>>(X, NPICK, count,
      wo1_bf, wo2_bf, b_out1, b_out2, out);
}